// Round 3
// baseline (1387.150 us; speedup 1.0000x reference)
//
#include <hip/hip_runtime.h>
#include <hip/hip_bf16.h>

#define DEVI __device__ __forceinline__

typedef _Float16 f16_t;
typedef f16_t f16x8 __attribute__((ext_vector_type(8)));
typedef f16_t f16x4 __attribute__((ext_vector_type(4)));
typedef float f32x4 __attribute__((ext_vector_type(4)));

static constexpr int B_ = 8, S_ = 4096, F_ = 1024, H_ = 1024;

DEVI void gload_lds16(const void* g, void* l) {
  __builtin_amdgcn_global_load_lds(
      (const __attribute__((address_space(1))) unsigned int*)g,
      (__attribute__((address_space(3))) unsigned int*)l, 16, 0, 0);
}

// ---------------------------------------------------------------------------
// Segmented NT GEMM: C[m,n] = sum_seg sum_k Aseg[m,k] * Bseg[n,k]
// 128x128 tile, BK=64, 512 threads (8 waves, 2Mx4N; per-wave 64x32 out),
// double-buffered LDS, stage-next-before-compute, ONE barrier per K-step.
// MODE: 0 = f32 out, 1 = f16 out, 2 = split-f16 out (hi at C, lo at C+noff),
// 3 = f32 out + bias[col].
// ---------------------------------------------------------------------------
template <int MODE>
__global__ __launch_bounds__(512, 4) void gemm_nt(
    const f16_t* __restrict__ A0, const f16_t* __restrict__ A1,
    const f16_t* __restrict__ A2, const f16_t* __restrict__ B0,
    const f16_t* __restrict__ B1, const f16_t* __restrict__ B2,
    void* __restrict__ Cout, const float* __restrict__ bias,
    int Kseg, int nseg, int ldA, int ldB,
    long sA, long sB, long sC, int ldc, long noff)
{
  const int bz = blockIdx.z;
  const int tid = threadIdx.x;
  const int wave = tid >> 6, lane = tid & 63;
  const int wr = wave >> 2, wc = wave & 3;
  const long bm = (long)blockIdx.x * 128, bn = (long)blockIdx.y * 128;

  __shared__ f16_t As[2][128 * 64];
  __shared__ f16_t Bs[2][128 * 64];

  f32x4 acc[4][2] = {};

  const size_t lda_b = (size_t)ldA * 2;
  const size_t ldb_b = (size_t)ldB * 2;

  const char* A0b = (const char*)(A0 + (size_t)bz * sA);
  const char* A1b = (const char*)(A1 + (size_t)bz * sA);
  const char* A2b = (const char*)(A2 + (size_t)bz * sA);
  const char* B0b = (const char*)(B0 + (size_t)bz * sB);
  const char* B1b = (const char*)(B1 + (size_t)bz * sB);
  const char* B2b = (const char*)(B2 + (size_t)bz * sB);

  const int nsteps = nseg * (Kseg >> 6);

  auto stage = [&](int buf, int sg, int kt) {
    const char* Ap = (sg == 0) ? A0b : (sg == 1) ? A1b : A2b;
    const char* Bp = (sg == 0) ? B0b : (sg == 1) ? B1b : B2b;
    Ap += (size_t)kt * 2;
    Bp += (size_t)kt * 2;
#pragma unroll
    for (int j = 0; j < 2; ++j) {
      const int base = wave * 2048 + j * 1024;  // wave-uniform LDS dest
      const int off = base + lane * 16;
      const int row = off >> 7, colb = off & 127;
      gload_lds16(Ap + (size_t)(bm + row) * lda_b + colb, (char*)As[buf] + base);
      gload_lds16(Bp + (size_t)(bn + row) * ldb_b + colb, (char*)Bs[buf] + base);
    }
  };

  stage(0, 0, 0);
  __syncthreads();  // drains vmcnt(0): buf0 ready

  int seg = 0, kt = 0, cur = 0;
  for (int t = 0; t < nsteps; ++t) {
    int kt2 = kt + 64, seg2 = seg;
    if (kt2 == Kseg) { kt2 = 0; seg2 = seg + 1; }
    if (t + 1 < nsteps) stage(cur ^ 1, seg2, kt2);  // prefetch next tile
#pragma unroll
    for (int kk = 0; kk < 2; ++kk) {
      f16x8 af[4], bg[2];
#pragma unroll
      for (int m = 0; m < 4; ++m) {
        const int row = wr * 64 + m * 16 + (lane & 15);
        af[m] = *(const f16x8*)((const char*)As[cur] + row * 128 + kk * 64 + (lane >> 4) * 16);
      }
#pragma unroll
      for (int n = 0; n < 2; ++n) {
        const int row = wc * 32 + n * 16 + (lane & 15);
        bg[n] = *(const f16x8*)((const char*)Bs[cur] + row * 128 + kk * 64 + (lane >> 4) * 16);
      }
#pragma unroll
      for (int m = 0; m < 4; ++m)
#pragma unroll
        for (int n = 0; n < 2; ++n)
          acc[m][n] = __builtin_amdgcn_mfma_f32_16x16x32_f16(af[m], bg[n], acc[m][n], 0, 0, 0);
    }
    __syncthreads();  // drains this step's prefetch (vmcnt 0) + lgkm; swap
    cur ^= 1; seg = seg2; kt = kt2;
  }

  // C/D layout (verified m89/m91): col = lane&15, row = (lane>>4)*4 + j
  const int r0 = (lane >> 4) * 4;
  const int c0 = lane & 15;
#pragma unroll
  for (int m = 0; m < 4; ++m) {
#pragma unroll
    for (int n = 0; n < 2; ++n) {
      const long col = bn + wc * 32 + n * 16 + c0;
      float bcol = 0.f;
      if (MODE == 3) bcol = bias[col];
#pragma unroll
      for (int j = 0; j < 4; ++j) {
        const long row = bm + wr * 64 + m * 16 + r0 + j;
        const float vv = acc[m][n][j];
        if (MODE == 0 || MODE == 3) {
          ((float*)Cout)[(long)bz * sC + row * ldc + col] = vv + bcol;
        } else if (MODE == 1) {
          ((f16_t*)Cout)[(long)bz * sC + row * ldc + col] = (f16_t)vv;
        } else {
          f16_t hi = (f16_t)vv;
          float lo = vv - (float)hi;
          f16_t* C = (f16_t*)Cout + (long)bz * sC + row * ldc + col;
          C[0] = hi;
          C[noff] = (f16_t)lo;
        }
      }
    }
  }
}

// ---------------------------------------------------------------------------
// x (f32 [B,S,F]) -> Xf f16 [B,S,F] and Xt f16 [B,F,S] (transposed)
// ---------------------------------------------------------------------------
__global__ __launch_bounds__(256) void conv_x(const float* __restrict__ x,
                                              f16_t* __restrict__ Xf,
                                              f16_t* __restrict__ Xt)
{
  const int b = blockIdx.z;
  const int s0 = blockIdx.x * 64, f0 = blockIdx.y * 64;
  const float* xb = x + (size_t)b * S_ * F_;
  f16_t* Xfb = Xf + (size_t)b * S_ * F_;
  f16_t* Xtb = Xt + (size_t)b * S_ * F_;
  __shared__ f16_t tile[64][72];
  const int tid = threadIdx.x;
#pragma unroll
  for (int i = 0; i < 4; ++i) {
    const int idx = i * 256 + tid;
    const int r = idx >> 4, c4 = idx & 15;
    f32x4 v = *(const f32x4*)(xb + (size_t)(s0 + r) * F_ + f0 + c4 * 4);
    f16x4 h;
    h[0] = (f16_t)v[0]; h[1] = (f16_t)v[1];
    h[2] = (f16_t)v[2]; h[3] = (f16_t)v[3];
    *(f16x4*)(Xfb + (size_t)(s0 + r) * F_ + f0 + c4 * 4) = h;
    *(f16x4*)(&tile[r][c4 * 4]) = h;
  }
  __syncthreads();
#pragma unroll
  for (int i = 0; i < 2; ++i) {
    const int idx = i * 256 + tid;
    const int r = idx >> 3, c8 = idx & 7;
    f16x8 o;
#pragma unroll
    for (int j = 0; j < 8; ++j) o[j] = tile[c8 * 8 + j][r];
    *(f16x8*)(Xtb + (size_t)(f0 + r) * S_ + s0 + c8 * 8) = o;
  }
}

// Wq,Wk f32 [F,F] -> hi/lo split f16; Wv f32 -> f16.
__global__ __launch_bounds__(256) void conv_w(const float* __restrict__ Wq,
    const float* __restrict__ Wk, const float* __restrict__ Wv,
    f16_t* __restrict__ Wqh, f16_t* __restrict__ Wql,
    f16_t* __restrict__ Wkh, f16_t* __restrict__ Wkl,
    f16_t* __restrict__ Wvh)
{
  const int idx = blockIdx.x * 256 + threadIdx.x;
  const int e = idx * 4;
  f32x4 q = *(const f32x4*)(Wq + e);
  f32x4 k = *(const f32x4*)(Wk + e);
  f32x4 w = *(const f32x4*)(Wv + e);
  f16x4 qh, ql, kh, kl, wh;
#pragma unroll
  for (int j = 0; j < 4; ++j) {
    f16_t h = (f16_t)q[j];
    qh[j] = h; ql[j] = (f16_t)(q[j] - (float)h);
    h = (f16_t)k[j];
    kh[j] = h; kl[j] = (f16_t)(k[j] - (float)h);
    wh[j] = (f16_t)w[j];
  }
  *(f16x4*)(Wqh + e) = qh;
  *(f16x4*)(Wql + e) = ql;
  *(f16x4*)(Wkh + e) = kh;
  *(f16x4*)(Wkl + e) = kl;
  *(f16x4*)(Wvh + e) = wh;
}

// c[b,f] = sum_s X[b,s,f]  (reads Xt rows, one wave per (b,f))
__global__ __launch_bounds__(256) void colsum_k(const f16_t* __restrict__ Xt,
                                                float* __restrict__ c)
{
  const int gw = blockIdx.x * 4 + (threadIdx.x >> 6);
  const int lane = threadIdx.x & 63;
  const f16_t* row = Xt + (size_t)gw * S_;
  float s = 0.f;
#pragma unroll
  for (int rep = 0; rep < 8; ++rep) {
    f16x8 v = *(const f16x8*)(row + rep * 512 + lane * 8);
#pragma unroll
    for (int j = 0; j < 8; ++j) s += (float)v[j];
  }
#pragma unroll
  for (int off = 32; off > 0; off >>= 1) s += __shfl_down(s, off);
  if (lane == 0) c[gw] = s;
}

// u[b,f] = sum_i Wq[f,i] c[b,i];  v[b,f] = sum_i Wk[f,i] c[b,i]  (fp32)
__global__ __launch_bounds__(256) void uv_k(const float* __restrict__ Wq,
    const float* __restrict__ Wk, const float* __restrict__ c,
    float* __restrict__ u, float* __restrict__ v)
{
  const int gw = blockIdx.x * 4 + (threadIdx.x >> 6);
  const int lane = threadIdx.x & 63;
  const int sel = gw >> 13;
  const int id = gw & 8191;
  const int b = id >> 10, f = id & 1023;
  const float* W = sel ? Wk : Wq;
  const float* wrow = W + (size_t)f * 1024;
  const float* crow = c + b * 1024;
  float s = 0.f;
#pragma unroll
  for (int rep = 0; rep < 4; ++rep) {
    f32x4 wv = *(const f32x4*)(wrow + rep * 256 + lane * 4);
    f32x4 cv = *(const f32x4*)(crow + rep * 256 + lane * 4);
    s += wv[0] * cv[0] + wv[1] * cv[1] + wv[2] * cv[2] + wv[3] * cv[3];
  }
#pragma unroll
  for (int off = 32; off > 0; off >>= 1) s += __shfl_down(s, off);
  if (lane == 0) { (sel ? v : u)[id] = s; }
}

// softmax over g of  L[b,f,g] + u[b,f]*bk[g] + bq[f]*(v[b,g] + S*bk[g])
__global__ __launch_bounds__(256) void softmax_k(const float* __restrict__ L,
    const float* __restrict__ bq, const float* __restrict__ bk,
    const float* __restrict__ u, const float* __restrict__ v,
    f16_t* __restrict__ W)
{
  const int row = blockIdx.x;  // b*1024 + f
  const int b = row >> 10, f = row & 1023;
  const float* Lr = L + (size_t)row * 1024;
  const float uq = u[row], bqf = bq[f];
  const int tid = threadIdx.x;
  const int wave = tid >> 6, lane = tid & 63;

  f32x4 lv  = *(const f32x4*)(Lr + tid * 4);
  f32x4 bkv = *(const f32x4*)(bk + tid * 4);
  f32x4 vv  = *(const f32x4*)(v + b * 1024 + tid * 4);
  float lg[4];
#pragma unroll
  for (int j = 0; j < 4; ++j)
    lg[j] = lv[j] + uq * bkv[j] + bqf * (vv[j] + 4096.f * bkv[j]);

  __shared__ float red[8];
  float m = fmaxf(fmaxf(lg[0], lg[1]), fmaxf(lg[2], lg[3]));
#pragma unroll
  for (int off = 32; off > 0; off >>= 1) m = fmaxf(m, __shfl_down(m, off));
  if (lane == 0) red[wave] = m;
  __syncthreads();
  m = fmaxf(fmaxf(red[0], red[1]), fmaxf(red[2], red[3]));

  float p[4], s = 0.f;
#pragma unroll
  for (int j = 0; j < 4; ++j) { p[j] = __expf(lg[j] - m); s += p[j]; }
#pragma unroll
  for (int off = 32; off > 0; off >>= 1) s += __shfl_down(s, off);
  if (lane == 0) red[4 + wave] = s;
  __syncthreads();
  s = red[4] + red[5] + red[6] + red[7];
  const float inv = 1.f / s;
  f16x4 o;
#pragma unroll
  for (int j = 0; j < 4; ++j) o[j] = (f16_t)(p[j] * inv);
  *(f16x4*)(W + (size_t)row * 1024 + tid * 4) = o;
}

// ---------------------------------------------------------------------------
extern "C" void kernel_launch(void* const* d_in, const int* in_sizes, int n_in,
                              void* d_out, int out_size, void* d_ws, size_t ws_size,
                              hipStream_t stream)
{
  const float* x  = (const float*)d_in[0];
  const float* Wq = (const float*)d_in[1];
  const float* bq = (const float*)d_in[2];
  const float* Wk = (const float*)d_in[3];
  const float* bk = (const float*)d_in[4];
  const float* Wv = (const float*)d_in[5];
  const float* bv = (const float*)d_in[6];
  float* out = (float*)d_out;

  const size_t MB = 1024ull * 1024ull;
  char* ws = (char*)d_ws;
  // Workspace layout (171 MiB total, with overlays):
  f16_t* Xf  = (f16_t*)(ws);             // [0,64M)   until final GEMM
  f16_t* Xt  = (f16_t*)(ws + 64 * MB);   // [64,128M) dies after G/colsum
  float* Lf  = (float*)(ws + 64 * MB);   // [64,96M)  overlays Xt (after G)
  f16_t* Th  = (f16_t*)(ws + 96 * MB);   // [96,112M) overlays Xt
  f16_t* Tl  = (f16_t*)(ws + 112 * MB);  // [112,128M)
  f16_t* Wqh = (f16_t*)(ws + 128 * MB);  // 2 MiB each
  f16_t* Wql = (f16_t*)(ws + 130 * MB);
  f16_t* Wkh = (f16_t*)(ws + 132 * MB);
  f16_t* Wkl = (f16_t*)(ws + 134 * MB);
  f16_t* Wvh = (f16_t*)(ws + 136 * MB);
  float* csum = (float*)(ws + 138 * MB);
  float* uvec = (float*)(ws + 138 * MB + 64 * 1024);
  float* vvec = (float*)(ws + 138 * MB + 128 * 1024);
  f16_t* Gh  = (f16_t*)(ws + 139 * MB);  // [139,155M) -> Wsm after T1
  f16_t* Gl  = (f16_t*)(ws + 155 * MB);  // [155,171M) -> Mt after T1
  f16_t* Wsm = (f16_t*)(ws + 139 * MB);
  f16_t* Mt  = (f16_t*)(ws + 155 * MB);

  if (ws_size < 171 * MB) return;  // insufficient scratch

  const long M1 = 1024L * 1024L;   // per-batch F*F elements
  const long noffG = 8L * M1;      // Gh->Gl element offset
  const long noffT = 8L * M1;      // Th->Tl element offset

  dim3 blk(256);
  dim3 gblk(512);
  // 1. convert + transpose x
  conv_x<<<dim3(64, 16, 8), blk, 0, stream>>>(x, Xf, Xt);
  // 2. weights -> f16 hi/lo
  conv_w<<<dim3(1024), blk, 0, stream>>>(Wq, Wk, Wv, Wqh, Wql, Wkh, Wkl, Wvh);
  // 3. column sums of X (from Xt)
  colsum_k<<<dim3(2048), blk, 0, stream>>>(Xt, csum);
  // 4. u = Wq c, v = Wk c (fp32)
  uv_k<<<dim3(4096), blk, 0, stream>>>(Wq, Wk, csum, uvec, vvec);
  // 5. G = Xt Xt^T (f16 operands, fp32 acc), split f16 -> Gh,Gl
  gemm_nt<2><<<dim3(8, 8, 8), gblk, 0, stream>>>(Xt, Xt, Xt, Xt, Xt, Xt,
      Gh, nullptr, 4096, 1, 4096, 4096,
      (long)F_ * S_, (long)F_ * S_, M1, 1024, noffG);
  // 6. T = Wq G = Wqh*Gh + Wql*Gh + Wqh*Gl (G symmetric), split -> Th,Tl
  gemm_nt<2><<<dim3(8, 8, 8), gblk, 0, stream>>>(Wqh, Wql, Wqh, Gh, Gh, Gl,
      Th, nullptr, 1024, 3, 1024, 1024,
      0L, M1, M1, 1024, noffT);
  // 7. L = T Wk^T = Th*Wkh + Tl*Wkh + Th*Wkl -> f32 Lf
  gemm_nt<0><<<dim3(8, 8, 8), gblk, 0, stream>>>(Th, Tl, Th, Wkh, Wkh, Wkl,
      Lf, nullptr, 1024, 3, 1024, 1024,
      M1, 0L, M1, 1024, 0L);
  // 8. softmax rows (+ rank-1 bias terms) -> Wsm f16 (over dead Gh)
  softmax_k<<<dim3(8192), blk, 0, stream>>>(Lf, bq, bk, uvec, vvec, Wsm);
  // 9. Mt[h,f] = sum_g Wv[h,g] Wsm[f,g] -> f16 (over dead Gl)
  gemm_nt<1><<<dim3(8, 8, 8), gblk, 0, stream>>>(Wvh, Wvh, Wvh, Wsm, Wsm, Wsm,
      Mt, nullptr, 1024, 1, 1024, 1024,
      0L, M1, M1, 1024, 0L);
  // 10. out[s,h] = sum_f X[s,f] Mt[h,f] + bv[h] -> f32 d_out
  gemm_nt<3><<<dim3(32, 8, 8), gblk, 0, stream>>>(Xf, Xf, Xf, Mt, Mt, Mt,
      out, bv, 1024, 1, 1024, 1024,
      (long)S_ * F_, M1, (long)S_ * H_, 1024, 0L);
}

// Round 5
// 590.109 us; speedup vs baseline: 2.3507x; 2.3507x over previous
//
#include <hip/hip_runtime.h>
#include <hip/hip_bf16.h>

#define DEVI __device__ __forceinline__

typedef _Float16 f16_t;
typedef f16_t f16x8 __attribute__((ext_vector_type(8)));
typedef f16_t f16x4 __attribute__((ext_vector_type(4)));
typedef float f32x4 __attribute__((ext_vector_type(4)));

static constexpr int B_ = 8, S_ = 4096, F_ = 1024, H_ = 1024;

DEVI void gload_lds16(const void* g, void* l) {
  __builtin_amdgcn_global_load_lds(
      (const __attribute__((address_space(1))) unsigned int*)g,
      (__attribute__((address_space(3))) unsigned int*)l, 16, 0, 0);
}

// ---------------------------------------------------------------------------
// Segmented NT GEMM: C[m,n] = sum_seg sum_k Aseg[m,k] * Bseg[n,k]
// 128x128 tile, BK=64, 256 threads (4 waves, 2x2; per-wave 64x64 out).
// Round-2 proven structure + T2 XOR swizzle:
//   LDS[row][chunk] holds global[row][chunk ^ (row&7)]  (16B chunks).
//   global_load_lds writes linearly -> inverse-swizzle the GLOBAL source;
//   ds_read applies the same XOR.  (rule #21: both-sides-or-neither)
// MODE: 0 = f32 out, 1 = f16 out, 2 = split-f16 out (hi at C, lo at C+noff),
// 3 = f32 out + bias[col].
// ---------------------------------------------------------------------------
template <int MODE>
__global__ __launch_bounds__(256, 2) void gemm_nt(
    const f16_t* __restrict__ A0, const f16_t* __restrict__ A1,
    const f16_t* __restrict__ A2, const f16_t* __restrict__ B0,
    const f16_t* __restrict__ B1, const f16_t* __restrict__ B2,
    void* __restrict__ Cout, const float* __restrict__ bias,
    int Kseg, int nseg, int ldA, int ldB,
    long sA, long sB, long sC, int ldc, long noff)
{
  const int bz = blockIdx.z;
  const f16_t* Ab[3] = {A0 + (size_t)bz * sA, A1 + (size_t)bz * sA,
                        A2 + (size_t)bz * sA};
  const f16_t* Bb[3] = {B0 + (size_t)bz * sB, B1 + (size_t)bz * sB,
                        B2 + (size_t)bz * sB};
  const int tid = threadIdx.x;
  const int wave = tid >> 6, lane = tid & 63;
  const int wr = wave >> 1, wc = wave & 1;
  const long bm = (long)blockIdx.x * 128, bn = (long)blockIdx.y * 128;

  __shared__ f16_t As[128 * 64];
  __shared__ f16_t Bs[128 * 64];

  f32x4 acc[4][4] = {};

  const size_t lda_b = (size_t)ldA * 2;
  const size_t ldb_b = (size_t)ldB * 2;

  for (int seg = 0; seg < nseg; ++seg) {
    const char* Aseg = (const char*)Ab[seg];
    const char* Bseg = (const char*)Bb[seg];
    for (int kt = 0; kt < Kseg; kt += 64) {
      __syncthreads();
#pragma unroll
      for (int j = 0; j < 4; ++j) {
        const int base = j * 4096 + wave * 1024;  // wave-uniform LDS dest
        const int off = base + lane * 16;
        const int row = off >> 7;
        const int colb = (off & 127) ^ ((row & 7) << 4);  // inverse swizzle
        gload_lds16(Aseg + (size_t)(bm + row) * lda_b + (size_t)kt * 2 + colb,
                    (char*)As + base);
      }
#pragma unroll
      for (int j = 0; j < 4; ++j) {
        const int base = j * 4096 + wave * 1024;
        const int off = base + lane * 16;
        const int row = off >> 7;
        const int colb = (off & 127) ^ ((row & 7) << 4);
        gload_lds16(Bseg + (size_t)(bn + row) * ldb_b + (size_t)kt * 2 + colb,
                    (char*)Bs + base);
      }
      __syncthreads();
#pragma unroll
      for (int kk = 0; kk < 2; ++kk) {
        f16x8 af[4], bg[4];
#pragma unroll
        for (int m = 0; m < 4; ++m) {
          const int row = wr * 64 + m * 16 + (lane & 15);
          const int coff = (kk * 64 + (lane >> 4) * 16) ^ ((row & 7) << 4);
          af[m] = *(const f16x8*)((const char*)As + row * 128 + coff);
        }
#pragma unroll
        for (int n = 0; n < 4; ++n) {
          const int row = wc * 64 + n * 16 + (lane & 15);
          const int coff = (kk * 64 + (lane >> 4) * 16) ^ ((row & 7) << 4);
          bg[n] = *(const f16x8*)((const char*)Bs + row * 128 + coff);
        }
#pragma unroll
        for (int m = 0; m < 4; ++m)
#pragma unroll
          for (int n = 0; n < 4; ++n)
            acc[m][n] = __builtin_amdgcn_mfma_f32_16x16x32_f16(af[m], bg[n], acc[m][n], 0, 0, 0);
      }
    }
  }

  // C/D layout (verified m89/m91): col = lane&15, row = (lane>>4)*4 + j
  const int r0 = (lane >> 4) * 4;
  const int c0 = lane & 15;
#pragma unroll
  for (int m = 0; m < 4; ++m) {
#pragma unroll
    for (int n = 0; n < 4; ++n) {
      const long col = bn + wc * 64 + n * 16 + c0;
      float bcol = 0.f;
      if (MODE == 3) bcol = bias[col];
#pragma unroll
      for (int j = 0; j < 4; ++j) {
        const long row = bm + wr * 64 + m * 16 + r0 + j;
        const float vv = acc[m][n][j];
        if (MODE == 0 || MODE == 3) {
          ((float*)Cout)[(long)bz * sC + row * ldc + col] = vv + bcol;
        } else if (MODE == 1) {
          ((f16_t*)Cout)[(long)bz * sC + row * ldc + col] = (f16_t)vv;
        } else {
          f16_t hi = (f16_t)vv;
          float lo = vv - (float)hi;
          f16_t* C = (f16_t*)Cout + (long)bz * sC + row * ldc + col;
          C[0] = hi;
          C[noff] = (f16_t)lo;
        }
      }
    }
  }
}

// ---------------------------------------------------------------------------
// x (f32 [B,S,F]) -> Xf f16 [B,S,F] and Xt f16 [B,F,S] (transposed)
// ---------------------------------------------------------------------------
__global__ __launch_bounds__(256) void conv_x(const float* __restrict__ x,
                                              f16_t* __restrict__ Xf,
                                              f16_t* __restrict__ Xt)
{
  const int b = blockIdx.z;
  const int s0 = blockIdx.x * 64, f0 = blockIdx.y * 64;
  const float* xb = x + (size_t)b * S_ * F_;
  f16_t* Xfb = Xf + (size_t)b * S_ * F_;
  f16_t* Xtb = Xt + (size_t)b * S_ * F_;
  __shared__ f16_t tile[64][72];
  const int tid = threadIdx.x;
#pragma unroll
  for (int i = 0; i < 4; ++i) {
    const int idx = i * 256 + tid;
    const int r = idx >> 4, c4 = idx & 15;
    f32x4 v = *(const f32x4*)(xb + (size_t)(s0 + r) * F_ + f0 + c4 * 4);
    f16x4 h;
    h[0] = (f16_t)v[0]; h[1] = (f16_t)v[1];
    h[2] = (f16_t)v[2]; h[3] = (f16_t)v[3];
    *(f16x4*)(Xfb + (size_t)(s0 + r) * F_ + f0 + c4 * 4) = h;
    *(f16x4*)(&tile[r][c4 * 4]) = h;
  }
  __syncthreads();
#pragma unroll
  for (int i = 0; i < 2; ++i) {
    const int idx = i * 256 + tid;
    const int r = idx >> 3, c8 = idx & 7;
    f16x8 o;
#pragma unroll
    for (int j = 0; j < 8; ++j) o[j] = tile[c8 * 8 + j][r];
    *(f16x8*)(Xtb + (size_t)(f0 + r) * S_ + s0 + c8 * 8) = o;
  }
}

// Wq,Wk f32 [F,F] -> hi/lo split f16; Wv f32 -> f16.
__global__ __launch_bounds__(256) void conv_w(const float* __restrict__ Wq,
    const float* __restrict__ Wk, const float* __restrict__ Wv,
    f16_t* __restrict__ Wqh, f16_t* __restrict__ Wql,
    f16_t* __restrict__ Wkh, f16_t* __restrict__ Wkl,
    f16_t* __restrict__ Wvh)
{
  const int idx = blockIdx.x * 256 + threadIdx.x;
  const int e = idx * 4;
  f32x4 q = *(const f32x4*)(Wq + e);
  f32x4 k = *(const f32x4*)(Wk + e);
  f32x4 w = *(const f32x4*)(Wv + e);
  f16x4 qh, ql, kh, kl, wh;
#pragma unroll
  for (int j = 0; j < 4; ++j) {
    f16_t h = (f16_t)q[j];
    qh[j] = h; ql[j] = (f16_t)(q[j] - (float)h);
    h = (f16_t)k[j];
    kh[j] = h; kl[j] = (f16_t)(k[j] - (float)h);
    wh[j] = (f16_t)w[j];
  }
  *(f16x4*)(Wqh + e) = qh;
  *(f16x4*)(Wql + e) = ql;
  *(f16x4*)(Wkh + e) = kh;
  *(f16x4*)(Wkl + e) = kl;
  *(f16x4*)(Wvh + e) = wh;
}

// c[b,f] = sum_s X[b,s,f]  (reads Xt rows, one wave per (b,f))
__global__ __launch_bounds__(256) void colsum_k(const f16_t* __restrict__ Xt,
                                                float* __restrict__ c)
{
  const int gw = blockIdx.x * 4 + (threadIdx.x >> 6);
  const int lane = threadIdx.x & 63;
  const f16_t* row = Xt + (size_t)gw * S_;
  float s = 0.f;
#pragma unroll
  for (int rep = 0; rep < 8; ++rep) {
    f16x8 v = *(const f16x8*)(row + rep * 512 + lane * 8);
#pragma unroll
    for (int j = 0; j < 8; ++j) s += (float)v[j];
  }
#pragma unroll
  for (int off = 32; off > 0; off >>= 1) s += __shfl_down(s, off);
  if (lane == 0) c[gw] = s;
}

// u[b,f] = sum_i Wq[f,i] c[b,i];  v[b,f] = sum_i Wk[f,i] c[b,i]  (fp32)
__global__ __launch_bounds__(256) void uv_k(const float* __restrict__ Wq,
    const float* __restrict__ Wk, const float* __restrict__ c,
    float* __restrict__ u, float* __restrict__ v)
{
  const int gw = blockIdx.x * 4 + (threadIdx.x >> 6);
  const int lane = threadIdx.x & 63;
  const int sel = gw >> 13;
  const int id = gw & 8191;
  const int b = id >> 10, f = id & 1023;
  const float* W = sel ? Wk : Wq;
  const float* wrow = W + (size_t)f * 1024;
  const float* crow = c + b * 1024;
  float s = 0.f;
#pragma unroll
  for (int rep = 0; rep < 4; ++rep) {
    f32x4 wv = *(const f32x4*)(wrow + rep * 256 + lane * 4);
    f32x4 cv = *(const f32x4*)(crow + rep * 256 + lane * 4);
    s += wv[0] * cv[0] + wv[1] * cv[1] + wv[2] * cv[2] + wv[3] * cv[3];
  }
#pragma unroll
  for (int off = 32; off > 0; off >>= 1) s += __shfl_down(s, off);
  if (lane == 0) { (sel ? v : u)[id] = s; }
}

// softmax over g of  L[b,f,g] + u[b,f]*bk[g] + bq[f]*(v[b,g] + S*bk[g])
__global__ __launch_bounds__(256) void softmax_k(const float* __restrict__ L,
    const float* __restrict__ bq, const float* __restrict__ bk,
    const float* __restrict__ u, const float* __restrict__ v,
    f16_t* __restrict__ W)
{
  const int row = blockIdx.x;  // b*1024 + f
  const int b = row >> 10, f = row & 1023;
  const float* Lr = L + (size_t)row * 1024;
  const float uq = u[row], bqf = bq[f];
  const int tid = threadIdx.x;
  const int wave = tid >> 6, lane = tid & 63;

  f32x4 lv  = *(const f32x4*)(Lr + tid * 4);
  f32x4 bkv = *(const f32x4*)(bk + tid * 4);
  f32x4 vv  = *(const f32x4*)(v + b * 1024 + tid * 4);
  float lg[4];
#pragma unroll
  for (int j = 0; j < 4; ++j)
    lg[j] = lv[j] + uq * bkv[j] + bqf * (vv[j] + 4096.f * bkv[j]);

  __shared__ float red[8];
  float m = fmaxf(fmaxf(lg[0], lg[1]), fmaxf(lg[2], lg[3]));
#pragma unroll
  for (int off = 32; off > 0; off >>= 1) m = fmaxf(m, __shfl_down(m, off));
  if (lane == 0) red[wave] = m;
  __syncthreads();
  m = fmaxf(fmaxf(red[0], red[1]), fmaxf(red[2], red[3]));

  float p[4], s = 0.f;
#pragma unroll
  for (int j = 0; j < 4; ++j) { p[j] = __expf(lg[j] - m); s += p[j]; }
#pragma unroll
  for (int off = 32; off > 0; off >>= 1) s += __shfl_down(s, off);
  if (lane == 0) red[4 + wave] = s;
  __syncthreads();
  s = red[4] + red[5] + red[6] + red[7];
  const float inv = 1.f / s;
  f16x4 o;
#pragma unroll
  for (int j = 0; j < 4; ++j) o[j] = (f16_t)(p[j] * inv);
  *(f16x4*)(W + (size_t)row * 1024 + tid * 4) = o;
}

// ---------------------------------------------------------------------------
extern "C" void kernel_launch(void* const* d_in, const int* in_sizes, int n_in,
                              void* d_out, int out_size, void* d_ws, size_t ws_size,
                              hipStream_t stream)
{
  const float* x  = (const float*)d_in[0];
  const float* Wq = (const float*)d_in[1];
  const float* bq = (const float*)d_in[2];
  const float* Wk = (const float*)d_in[3];
  const float* bk = (const float*)d_in[4];
  const float* Wv = (const float*)d_in[5];
  const float* bv = (const float*)d_in[6];
  float* out = (float*)d_out;

  const size_t MB = 1024ull * 1024ull;
  char* ws = (char*)d_ws;
  // Workspace layout (171 MiB total, with overlays):
  f16_t* Xf  = (f16_t*)(ws);             // [0,64M)   until final GEMM
  f16_t* Xt  = (f16_t*)(ws + 64 * MB);   // [64,128M) dies after G/colsum
  float* Lf  = (float*)(ws + 64 * MB);   // [64,96M)  overlays Xt (after G)
  f16_t* Th  = (f16_t*)(ws + 96 * MB);   // [96,112M) overlays Xt
  f16_t* Tl  = (f16_t*)(ws + 112 * MB);  // [112,128M)
  f16_t* Wqh = (f16_t*)(ws + 128 * MB);  // 2 MiB each
  f16_t* Wql = (f16_t*)(ws + 130 * MB);
  f16_t* Wkh = (f16_t*)(ws + 132 * MB);
  f16_t* Wkl = (f16_t*)(ws + 134 * MB);
  f16_t* Wvh = (f16_t*)(ws + 136 * MB);
  float* csum = (float*)(ws + 138 * MB);
  float* uvec = (float*)(ws + 138 * MB + 64 * 1024);
  float* vvec = (float*)(ws + 138 * MB + 128 * 1024);
  f16_t* Gh  = (f16_t*)(ws + 139 * MB);  // [139,155M) -> Wsm after T1
  f16_t* Gl  = (f16_t*)(ws + 155 * MB);  // [155,171M) -> Mt after T1
  f16_t* Wsm = (f16_t*)(ws + 139 * MB);
  f16_t* Mt  = (f16_t*)(ws + 155 * MB);

  if (ws_size < 171 * MB) return;  // insufficient scratch

  const long M1 = 1024L * 1024L;   // per-batch F*F elements
  const long noffG = 8L * M1;      // Gh->Gl element offset
  const long noffT = 8L * M1;      // Th->Tl element offset

  dim3 blk(256);
  // 1. convert + transpose x
  conv_x<<<dim3(64, 16, 8), blk, 0, stream>>>(x, Xf, Xt);
  // 2. weights -> f16 hi/lo
  conv_w<<<dim3(1024), blk, 0, stream>>>(Wq, Wk, Wv, Wqh, Wql, Wkh, Wkl, Wvh);
  // 3. column sums of X (from Xt)
  colsum_k<<<dim3(2048), blk, 0, stream>>>(Xt, csum);
  // 4. u = Wq c, v = Wk c (fp32)
  uv_k<<<dim3(4096), blk, 0, stream>>>(Wq, Wk, csum, uvec, vvec);
  // 5. G = Xt Xt^T (f16 operands, fp32 acc), split f16 -> Gh,Gl
  gemm_nt<2><<<dim3(8, 8, 8), blk, 0, stream>>>(Xt, Xt, Xt, Xt, Xt, Xt,
      Gh, nullptr, 4096, 1, 4096, 4096,
      (long)F_ * S_, (long)F_ * S_, M1, 1024, noffG);
  // 6. T = Wq G = Wqh*Gh + Wql*Gh + Wqh*Gl (G symmetric), split -> Th,Tl
  gemm_nt<2><<<dim3(8, 8, 8), blk, 0, stream>>>(Wqh, Wql, Wqh, Gh, Gh, Gl,
      Th, nullptr, 1024, 3, 1024, 1024,
      0L, M1, M1, 1024, noffT);
  // 7. L = T Wk^T = Th*Wkh + Tl*Wkh + Th*Wkl -> f32 Lf
  gemm_nt<0><<<dim3(8, 8, 8), blk, 0, stream>>>(Th, Tl, Th, Wkh, Wkh, Wkl,
      Lf, nullptr, 1024, 3, 1024, 1024,
      M1, 0L, M1, 1024, 0L);
  // 8. softmax rows (+ rank-1 bias terms) -> Wsm f16 (over dead Gh)
  softmax_k<<<dim3(8192), blk, 0, stream>>>(Lf, bq, bk, uvec, vvec, Wsm);
  // 9. Mt[h,f] = sum_g Wv[h,g] Wsm[f,g] -> f16 (over dead Gl)
  gemm_nt<1><<<dim3(8, 8, 8), blk, 0, stream>>>(Wvh, Wvh, Wvh, Wsm, Wsm, Wsm,
      Mt, nullptr, 1024, 1, 1024, 1024,
      0L, M1, M1, 1024, 0L);
  // 10. out[s,h] = sum_f X[s,f] Mt[h,f] + bv[h] -> f32 d_out
  gemm_nt<3><<<dim3(32, 8, 8), blk, 0, stream>>>(Xf, Xf, Xf, Mt, Mt, Mt,
      out, bv, 1024, 1, 1024, 1024,
      (long)S_ * F_, M1, (long)S_ * H_, 1024, 0L);
}